// Round 1
// baseline (1103.629 us; speedup 1.0000x reference)
//
#include <hip/hip_runtime.h>

// Problem constants
#define NB 64
#define HW 4096           // 64*64
#define W64 64

// ---------------------------------------------------------------------------
// K1: perceive (fixed stencil) + pre_life + zero the atomic accumulators.
// x: [B,64,64,8] HWC.  y_chw: [B,24,64,64].  y0_hwc: [98304] (batch 0, HWC order).
// prelife: [B*4096] float 0/1.  att_zero: 649 floats (648 att acc + 1 ssq).
// ---------------------------------------------------------------------------
__global__ __launch_bounds__(256) void k_perceive(
    const float* __restrict__ x, float* __restrict__ y_chw,
    float* __restrict__ y0_hwc, float* __restrict__ prelife,
    float* __restrict__ att_zero) {
  int t = threadIdx.x;
  if (blockIdx.x == 0) {
    for (int i = t; i < 649; i += 256) att_zero[i] = 0.f;
  }
  int pix = blockIdx.x * 256 + t;
  int b = pix >> 12;
  int hw = pix & 4095;
  int h = hw >> 6, w = hw & 63;
  const float* xp = x + (size_t)pix * 8;
  bool hm = h > 0, hp = h < 63, wm = w > 0, wp = w < 63;

  // pre_life: 3x3 maxpool of alpha (channel 3) on original x, SAME/-inf pad
  float mx = -1e30f;
  #pragma unroll
  for (int di = -1; di <= 1; ++di) {
    if ((unsigned)(h + di) > 63u) continue;
    #pragma unroll
    for (int dj = -1; dj <= 1; ++dj) {
      if ((unsigned)(w + dj) > 63u) continue;
      mx = fmaxf(mx, xp[(di * 64 + dj) * 8 + 3]);
    }
  }
  prelife[pix] = (mx > 0.1f) ? 1.f : 0.f;

  float* yb = y_chw + (size_t)b * 24 * HW + hw;
  bool b0 = (b == 0);
  #pragma unroll
  for (int c = 0; c < 8; ++c) {
    float ctr = xp[c];
    float a00 = (hm && wm) ? xp[(-65) * 8 + c] : 0.f;
    float a02 = (hm && wp) ? xp[(-63) * 8 + c] : 0.f;
    float a20 = (hp && wm) ? xp[(63) * 8 + c] : 0.f;
    float a22 = (hp && wp) ? xp[(65) * 8 + c] : 0.f;
    float d = (a00 + a02 + a20 + a22) * 0.125f;   // dxk == dyk (symmetric)
    yb[(size_t)(c * 3 + 0) * HW] = ctr;
    yb[(size_t)(c * 3 + 1) * HW] = d;
    yb[(size_t)(c * 3 + 2) * HW] = d;
    if (b0) {
      float* y0p = y0_hwc + hw * 24 + c * 3;
      y0p[0] = ctr; y0p[1] = d; y0p[2] = d;
    }
  }
}

// ---------------------------------------------------------------------------
// K2: attention mat-vec, batch 0 only: att_acc[j] += sum_r y0[r]*W_att[r,j].
// 768 blocks x 128 rows each. Coalesced row reads; 648 atomics per block.
// ---------------------------------------------------------------------------
__global__ __launch_bounds__(256) void k_att(
    const float* __restrict__ y0, const float* __restrict__ Watt,
    float* __restrict__ att_acc) {
  int t = threadIdx.x;
  int r0 = blockIdx.x * 128;
  float a0 = 0.f, a1 = 0.f, a2 = 0.f;
  for (int r = 0; r < 128; ++r) {
    float yv = y0[r0 + r];
    const float* wr = Watt + (size_t)(r0 + r) * 648;
    a0 = fmaf(yv, wr[t], a0);
    a1 = fmaf(yv, wr[t + 256], a1);
    if (t < 136) a2 = fmaf(yv, wr[t + 512], a2);
  }
  atomicAdd(att_acc + t, a0);
  atomicAdd(att_acc + t + 256, a1);
  if (t < 136) atomicAdd(att_acc + t + 512, a2);
}

// ---------------------------------------------------------------------------
// K3: second depthwise conv with attention kernel y_sum = att_acc + b_att,
// reshaped [3,3,24,3]. Input y_chw[B,24,64,64] -> y2_chw[B,72,64,64].
// Also accumulates global sum of squares into ssq (att_acc[648]).
// ---------------------------------------------------------------------------
__global__ __launch_bounds__(256) void k_dw2(
    const float* __restrict__ y_chw, const float* __restrict__ att_acc,
    const float* __restrict__ b_att, float* __restrict__ y2,
    float* __restrict__ ssq) {
  __shared__ float ys[648];
  int t = threadIdx.x;
  for (int i = t; i < 648; i += 256) ys[i] = att_acc[i] + b_att[i];
  __syncthreads();

  int pix = blockIdx.x * 256 + t;
  int b = pix >> 12;
  int hw = pix & 4095;
  int h = hw >> 6, w = hw & 63;
  bool vh[3] = {h > 0, true, h < 63};
  bool vw[3] = {w > 0, true, w < 63};
  const float* yb = y_chw + (size_t)b * 24 * HW + hw;
  float* y2b = y2 + (size_t)b * 72 * HW + hw;
  float local = 0.f;

  for (int c = 0; c < 24; ++c) {
    float tap[9];
    #pragma unroll
    for (int di = 0; di < 3; ++di) {
      #pragma unroll
      for (int dj = 0; dj < 3; ++dj) {
        bool v = vh[di] && vw[dj];
        long off = (long)c * HW + (di - 1) * 64 + (dj - 1);
        tap[di * 3 + dj] = v ? yb[off] : 0.f;
      }
    }
    #pragma unroll
    for (int m = 0; m < 3; ++m) {
      float s = 0.f;
      #pragma unroll
      for (int k9 = 0; k9 < 9; ++k9) s = fmaf(tap[k9], ys[(k9 * 24 + c) * 3 + m], s);
      y2b[(size_t)(c * 3 + m) * HW] = s;
      local = fmaf(s, s, local);
    }
  }
  // wave + block-lite reduction, one atomic per wave
  #pragma unroll
  for (int off = 32; off; off >>= 1) local += __shfl_down(local, off, 64);
  if ((t & 63) == 0) atomicAdd(ssq, local);
}

// ---------------------------------------------------------------------------
// K4: conv1 3x3 VALID, 72->48.  y2_chw[B,72,64,64] -> h1_chw[B,48,62,62].
// L2 normalization folded in: h1 = inv*conv(y2,W1) + b1.
// Thread per output pixel, acc[48] in VGPRs, weights wave-uniform (s_load).
// ---------------------------------------------------------------------------
__global__ __launch_bounds__(256) void k_conv1(
    const float* __restrict__ y2, const float* __restrict__ W1,
    const float* __restrict__ b1, const float* __restrict__ ssqp,
    float* __restrict__ h1) {
  int idx = blockIdx.x * 256 + threadIdx.x;     // B*62*62 = 246016 exact
  int b = idx / 3844;
  int rem = idx - b * 3844;
  int i = rem / 62;
  int j = rem - i * 62;
  float inv = rsqrtf(fmaxf(ssqp[0], 1e-12f));
  float acc[48];
  #pragma unroll
  for (int o = 0; o < 48; ++o) acc[o] = 0.f;
  const float* yb = y2 + (size_t)b * 72 * HW;
  #pragma unroll
  for (int di = 0; di < 3; ++di) {
    #pragma unroll
    for (int dj = 0; dj < 3; ++dj) {
      const float* ip = yb + (i + di) * 64 + (j + dj);
      const float* wp = W1 + (di * 3 + dj) * 72 * 48;
      for (int c = 0; c < 72; ++c) {
        float v = ip[(size_t)c * HW];
        const float* w = wp + c * 48;
        #pragma unroll
        for (int o = 0; o < 48; ++o) acc[o] = fmaf(v, w[o], acc[o]);
      }
    }
  }
  float* hb = h1 + (size_t)b * 48 * 3844 + i * 62 + j;
  #pragma unroll
  for (int o = 0; o < 48; ++o) hb[(size_t)o * 3844] = fmaf(acc[o], inv, b1[o]);
}

// ---------------------------------------------------------------------------
// K5: conv_transpose 3x3 stride1 VALID == pad-2 correlation, NO kernel flip.
// h1_chw[B,48,62,62] -> h2_chw[B,48,64,64].  h2[i,j,o]=bt[o]+sum h1[i-2+di,j-2+dj,c]*Wt[di,dj,c,o]
// ---------------------------------------------------------------------------
__global__ __launch_bounds__(256) void k_convT(
    const float* __restrict__ h1, const float* __restrict__ Wt,
    const float* __restrict__ bt, float* __restrict__ h2) {
  int pix = blockIdx.x * 256 + threadIdx.x;
  int b = pix >> 12;
  int hw = pix & 4095;
  int i = hw >> 6, j = hw & 63;
  float acc[48];
  #pragma unroll
  for (int o = 0; o < 48; ++o) acc[o] = 0.f;
  const float* hb = h1 + (size_t)b * 48 * 3844;
  #pragma unroll
  for (int di = 0; di < 3; ++di) {
    int ii = i - 2 + di;
    bool vi = (unsigned)ii < 62u;
    #pragma unroll
    for (int dj = 0; dj < 3; ++dj) {
      int jj = j - 2 + dj;
      bool v = vi && ((unsigned)jj < 62u);
      const float* ip = hb + ii * 62 + jj;
      const float* wp = Wt + (di * 3 + dj) * 48 * 48;
      for (int c = 0; c < 48; ++c) {
        float val = v ? ip[(size_t)c * 3844] : 0.f;
        const float* w = wp + c * 48;
        #pragma unroll
        for (int o = 0; o < 48; ++o) acc[o] = fmaf(val, w[o], acc[o]);
      }
    }
  }
  float* ob = h2 + (size_t)b * 48 * HW + hw;
  #pragma unroll
  for (int o = 0; o < 48; ++o) ob[(size_t)o * HW] = acc[o] + bt[o];
}

// ---------------------------------------------------------------------------
// K6: fused 1x1 relu (48->128) -> 1x1 (128->8) -> masked residual update.
// h2_chw -> x2 (HWC) + alpha2 plane.
// ---------------------------------------------------------------------------
__global__ __launch_bounds__(256) void k_head(
    const float* __restrict__ h2, const float* __restrict__ W2,
    const float* __restrict__ b2, const float* __restrict__ W3,
    const float* __restrict__ b3, const float* __restrict__ x,
    const float* __restrict__ noise, float* __restrict__ x2,
    float* __restrict__ alpha2) {
  int pix = blockIdx.x * 256 + threadIdx.x;
  int b = pix >> 12;
  int hw = pix & 4095;
  float hr[48];
  const float* hb = h2 + (size_t)b * 48 * HW + hw;
  #pragma unroll
  for (int c = 0; c < 48; ++c) hr[c] = hb[(size_t)c * HW];
  float dx[8];
  #pragma unroll
  for (int k = 0; k < 8; ++k) dx[k] = b3[k];
  for (int o = 0; o < 128; ++o) {
    float s = b2[o];
    const float* w2 = W2 + o;                 // W2[c*128 + o]
    #pragma unroll
    for (int c = 0; c < 48; ++c) s = fmaf(hr[c], w2[c * 128], s);
    s = fmaxf(s, 0.f);
    const float* w3 = W3 + o * 8;
    #pragma unroll
    for (int k = 0; k < 8; ++k) dx[k] = fmaf(s, w3[k], dx[k]);
  }
  float mask = (noise[pix] <= 0.5f) ? 1.f : 0.f;
  const float* xp = x + (size_t)pix * 8;
  float* xo = x2 + (size_t)pix * 8;
  float a3 = 0.f;
  #pragma unroll
  for (int k = 0; k < 8; ++k) {
    float v = fmaf(dx[k], mask, xp[k]);
    xo[k] = v;
    if (k == 3) a3 = v;
  }
  alpha2[pix] = a3;
}

// ---------------------------------------------------------------------------
// K7: post_life maxpool + alive gating -> d_out
// ---------------------------------------------------------------------------
__global__ __launch_bounds__(256) void k_life(
    const float* __restrict__ x2, const float* __restrict__ alpha2,
    const float* __restrict__ prelife, float* __restrict__ out) {
  int pix = blockIdx.x * 256 + threadIdx.x;
  int hw = pix & 4095;
  int h = hw >> 6, w = hw & 63;
  const float* ab = alpha2 + (size_t)(pix - hw);
  float mx = -1e30f;
  #pragma unroll
  for (int di = -1; di <= 1; ++di) {
    if ((unsigned)(h + di) > 63u) continue;
    #pragma unroll
    for (int dj = -1; dj <= 1; ++dj) {
      if ((unsigned)(w + dj) > 63u) continue;
      mx = fmaxf(mx, ab[(h + di) * 64 + (w + dj)]);
    }
  }
  float life = (mx > 0.1f && prelife[pix] > 0.5f) ? 1.f : 0.f;
  const float* xp = x2 + (size_t)pix * 8;
  float* op = out + (size_t)pix * 8;
  #pragma unroll
  for (int k = 0; k < 8; ++k) op[k] = xp[k] * life;
}

// ---------------------------------------------------------------------------
extern "C" void kernel_launch(void* const* d_in, const int* in_sizes, int n_in,
                              void* d_out, int out_size, void* d_ws, size_t ws_size,
                              hipStream_t stream) {
  const float* x     = (const float*)d_in[0];
  const float* noise = (const float*)d_in[1];
  const float* Watt  = (const float*)d_in[2];
  const float* b_att = (const float*)d_in[3];
  const float* W1    = (const float*)d_in[4];
  const float* b1    = (const float*)d_in[5];
  const float* Wt    = (const float*)d_in[6];
  const float* bt    = (const float*)d_in[7];
  const float* W2    = (const float*)d_in[8];
  const float* b2    = (const float*)d_in[9];
  const float* W3    = (const float*)d_in[10];
  const float* b3    = (const float*)d_in[11];
  float* out = (float*)d_out;

  float* ws = (float*)d_ws;
  // workspace layout (floats)
  size_t o_y   = 0;                       // y_chw   [64*24*4096]  = 6291456
  size_t o_y2  = o_y + 6291456;           // y2_chw  [64*72*4096] = 18874368 ; reused for h2_chw
  size_t o_h1  = o_y2 + 18874368;         // h1_chw  [64*48*62*62] = 11808768
  size_t o_y0  = o_h1 + 11808768;         // y0_hwc  [98304]
  size_t o_pre = o_y0 + 98304;            // prelife [262144]
  size_t o_att = o_pre + 262144;          // att_acc [648] + ssq [1]
  float* y_chw   = ws + o_y;
  float* y2_chw  = ws + o_y2;
  float* h2_chw  = ws + o_y2;             // alias: y2 dead after k_conv1
  float* h1_chw  = ws + o_h1;
  float* y0_hwc  = ws + o_y0;
  float* prelife = ws + o_pre;
  float* att_acc = ws + o_att;
  float* ssq     = ws + o_att + 648;
  float* x2      = ws + o_y;              // alias: y dead after k_dw2
  float* alpha2  = ws + o_y + 2097152;

  k_perceive<<<1024, 256, 0, stream>>>(x, y_chw, y0_hwc, prelife, att_acc);
  k_att<<<768, 256, 0, stream>>>(y0_hwc, Watt, att_acc);
  k_dw2<<<1024, 256, 0, stream>>>(y_chw, att_acc, b_att, y2_chw, ssq);
  k_conv1<<<961, 256, 0, stream>>>(y2_chw, W1, b1, ssq, h1_chw);
  k_convT<<<1024, 256, 0, stream>>>(h1_chw, Wt, bt, h2_chw);
  k_head<<<1024, 256, 0, stream>>>(h2_chw, W2, b2, W3, b3, x, noise, x2, alpha2);
  k_life<<<1024, 256, 0, stream>>>(x2, alpha2, prelife, out);
}

// Round 2
// 1063.675 us; speedup vs baseline: 1.0376x; 1.0376x over previous
//
#include <hip/hip_runtime.h>

#define NB 64
#define HW 4096           // 64*64

// ---------------------------------------------------------------------------
// K1: perceive (fixed stencil) + pre_life + zero the atomic accumulators.
// ---------------------------------------------------------------------------
__global__ __launch_bounds__(256) void k_perceive(
    const float* __restrict__ x, float* __restrict__ y_chw,
    float* __restrict__ y0_hwc, float* __restrict__ prelife,
    float* __restrict__ att_zero) {
  int t = threadIdx.x;
  if (blockIdx.x == 0) {
    for (int i = t; i < 649; i += 256) att_zero[i] = 0.f;
  }
  int pix = blockIdx.x * 256 + t;
  int b = pix >> 12;
  int hw = pix & 4095;
  int h = hw >> 6, w = hw & 63;
  const float* xp = x + (size_t)pix * 8;
  bool hm = h > 0, hp = h < 63, wm = w > 0, wp = w < 63;

  float mx = -1e30f;
  #pragma unroll
  for (int di = -1; di <= 1; ++di) {
    if ((unsigned)(h + di) > 63u) continue;
    #pragma unroll
    for (int dj = -1; dj <= 1; ++dj) {
      if ((unsigned)(w + dj) > 63u) continue;
      mx = fmaxf(mx, xp[(di * 64 + dj) * 8 + 3]);
    }
  }
  prelife[pix] = (mx > 0.1f) ? 1.f : 0.f;

  float* yb = y_chw + (size_t)b * 24 * HW + hw;
  bool b0 = (b == 0);
  #pragma unroll
  for (int c = 0; c < 8; ++c) {
    float ctr = xp[c];
    float a00 = (hm && wm) ? xp[(-65) * 8 + c] : 0.f;
    float a02 = (hm && wp) ? xp[(-63) * 8 + c] : 0.f;
    float a20 = (hp && wm) ? xp[(63) * 8 + c] : 0.f;
    float a22 = (hp && wp) ? xp[(65) * 8 + c] : 0.f;
    float d = (a00 + a02 + a20 + a22) * 0.125f;   // dxk == dyk (symmetric)
    yb[(size_t)(c * 3 + 0) * HW] = ctr;
    yb[(size_t)(c * 3 + 1) * HW] = d;
    yb[(size_t)(c * 3 + 2) * HW] = d;
    if (b0) {
      float* y0p = y0_hwc + hw * 24 + c * 3;
      y0p[0] = ctr; y0p[1] = d; y0p[2] = d;
    }
  }
}

// ---------------------------------------------------------------------------
// K2: attention mat-vec, batch 0 only (reads 255 MB of W_att -> HBM-bound).
// ---------------------------------------------------------------------------
__global__ __launch_bounds__(256) void k_att(
    const float* __restrict__ y0, const float* __restrict__ Watt,
    float* __restrict__ att_acc) {
  int t = threadIdx.x;
  int r0 = blockIdx.x * 128;
  float a0 = 0.f, a1 = 0.f, a2 = 0.f;
  for (int r = 0; r < 128; ++r) {
    float yv = y0[r0 + r];
    const float* wr = Watt + (size_t)(r0 + r) * 648;
    a0 = fmaf(yv, wr[t], a0);
    a1 = fmaf(yv, wr[t + 256], a1);
    if (t < 136) a2 = fmaf(yv, wr[t + 512], a2);
  }
  atomicAdd(att_acc + t, a0);
  atomicAdd(att_acc + t + 256, a1);
  if (t < 136) atomicAdd(att_acc + t + 512, a2);
}

// ---------------------------------------------------------------------------
// K3: depthwise conv2 with attention kernel, LDS-tiled 16x16, SAME pad.
// y_chw[B,24,64,64] -> y2_chw[B,72,64,64]; accumulates global sum-of-squares.
// grid: 64 images x 16 tiles.
// ---------------------------------------------------------------------------
__global__ __launch_bounds__(256) void k_dw2(
    const float* __restrict__ y_chw, const float* __restrict__ att_acc,
    const float* __restrict__ b_att, float* __restrict__ y2,
    float* __restrict__ ssq) {
  __shared__ float ys[648];
  __shared__ float s[24 * 324];           // 18x18 patch x 24 channels
  int t = threadIdx.x;
  for (int i = t; i < 648; i += 256) ys[i] = att_acc[i] + b_att[i];

  int blk = blockIdx.x;
  int b = blk >> 4;
  int tile = blk & 15;
  int i0 = (tile >> 2) * 16;
  int j0 = (tile & 3) * 16;
  int ty = t >> 4, tx = t & 15;
  const float* yb = y_chw + (size_t)b * 24 * HW;

  // stage 18x18 patches (zero-filled SAME padding) for all 24 channels
  for (int idx = t; idx < 24 * 324; idx += 256) {
    int c = idx / 324;
    int pos = idx - c * 324;
    int r = pos / 18, col = pos - r * 18;
    int gr = i0 - 1 + r, gc = j0 - 1 + col;
    bool v = ((unsigned)gr < 64u) && ((unsigned)gc < 64u);
    s[idx] = v ? yb[(size_t)c * HW + gr * 64 + gc] : 0.f;
  }
  __syncthreads();

  float* y2b = y2 + (size_t)b * 72 * HW + (i0 + ty) * 64 + (j0 + tx);
  float local = 0.f;
  for (int c = 0; c < 24; ++c) {
    const float* sc = s + c * 324 + ty * 18 + tx;
    float tap[9];
    #pragma unroll
    for (int di = 0; di < 3; ++di)
      #pragma unroll
      for (int dj = 0; dj < 3; ++dj) tap[di * 3 + dj] = sc[di * 18 + dj];
    #pragma unroll
    for (int m = 0; m < 3; ++m) {
      float acc = 0.f;
      #pragma unroll
      for (int k9 = 0; k9 < 9; ++k9) acc = fmaf(tap[k9], ys[(k9 * 24 + c) * 3 + m], acc);
      y2b[(size_t)(c * 3 + m) * HW] = acc;
      local = fmaf(acc, acc, local);
    }
  }
  #pragma unroll
  for (int off = 32; off; off >>= 1) local += __shfl_down(local, off, 64);
  if ((t & 63) == 0) atomicAdd(ssq, local);
}

// ---------------------------------------------------------------------------
// K4: conv1 3x3 VALID 72->48, LDS-tiled. y2[B,72,64,64] -> h1[B,48,62,62].
// L2 norm folded: h1 = inv*conv(y2,W1) + b1. 16x16 output tile, channel
// chunks of 24 (31 KB LDS). Tiles clipped to 46 (overlap rows recompute
// identical values -> benign duplicate writes).
// ---------------------------------------------------------------------------
__global__ __launch_bounds__(256) void k_conv1(
    const float* __restrict__ y2, const float* __restrict__ W1,
    const float* __restrict__ b1, const float* __restrict__ ssqp,
    float* __restrict__ h1) {
  __shared__ float s[24 * 324];
  int t = threadIdx.x;
  int blk = blockIdx.x;
  int b = blk >> 4;
  int tile = blk & 15;
  int i0 = (tile >> 2) * 16; if (i0 > 46) i0 = 46;
  int j0 = (tile & 3) * 16;  if (j0 > 46) j0 = 46;
  int ty = t >> 4, tx = t & 15;

  float acc[48];
  #pragma unroll
  for (int o = 0; o < 48; ++o) acc[o] = 0.f;
  const float* yb = y2 + (size_t)b * 72 * HW;

  for (int c0 = 0; c0 < 72; c0 += 24) {
    __syncthreads();
    for (int idx = t; idx < 24 * 324; idx += 256) {
      int c = idx / 324;
      int pos = idx - c * 324;
      int r = pos / 18, col = pos - r * 18;
      s[idx] = yb[(size_t)(c0 + c) * HW + (i0 + r) * 64 + (j0 + col)];
    }
    __syncthreads();
    for (int c = 0; c < 24; ++c) {
      const float* sc = s + c * 324 + ty * 18 + tx;
      float tap[9];
      #pragma unroll
      for (int di = 0; di < 3; ++di)
        #pragma unroll
        for (int dj = 0; dj < 3; ++dj) tap[di * 3 + dj] = sc[di * 18 + dj];
      #pragma unroll
      for (int k9 = 0; k9 < 9; ++k9) {
        const float* w = W1 + (size_t)(k9 * 72 + c0 + c) * 48;
        float tv = tap[k9];
        #pragma unroll
        for (int o = 0; o < 48; ++o) acc[o] = fmaf(tv, w[o], acc[o]);
      }
    }
  }
  float inv = rsqrtf(fmaxf(ssqp[0], 1e-12f));
  float* hb = h1 + (size_t)b * 48 * 3844 + (i0 + ty) * 62 + (j0 + tx);
  #pragma unroll
  for (int o = 0; o < 48; ++o) hb[(size_t)o * 3844] = fmaf(acc[o], inv, b1[o]);
}

// ---------------------------------------------------------------------------
// K5: conv_transpose 3x3 (pad-2 correlation, no flip) 48->48, LDS-tiled,
// FUSED with 1x1 relu (48->128) -> 1x1 (128->8) -> masked residual update.
// h1[B,48,62,62] -> x2 (HWC) + alpha2 plane. 16x16 output tile (64/16 exact).
// ---------------------------------------------------------------------------
__global__ __launch_bounds__(256) void k_convT_head(
    const float* __restrict__ h1, const float* __restrict__ Wt,
    const float* __restrict__ bt, const float* __restrict__ W2,
    const float* __restrict__ b2, const float* __restrict__ W3,
    const float* __restrict__ b3, const float* __restrict__ x,
    const float* __restrict__ noise, float* __restrict__ x2,
    float* __restrict__ alpha2) {
  __shared__ float s[24 * 324];
  int t = threadIdx.x;
  int blk = blockIdx.x;
  int b = blk >> 4;
  int tile = blk & 15;
  int i0 = (tile >> 2) * 16;
  int j0 = (tile & 3) * 16;
  int ty = t >> 4, tx = t & 15;

  float acc[48];
  #pragma unroll
  for (int o = 0; o < 48; ++o) acc[o] = 0.f;
  const float* hb = h1 + (size_t)b * 48 * 3844;

  for (int c0 = 0; c0 < 48; c0 += 24) {
    __syncthreads();
    for (int idx = t; idx < 24 * 324; idx += 256) {
      int c = idx / 324;
      int pos = idx - c * 324;
      int r = pos / 18, col = pos - r * 18;
      int gr = i0 - 2 + r, gc = j0 - 2 + col;     // input coords in [0,62)
      bool v = ((unsigned)gr < 62u) && ((unsigned)gc < 62u);
      s[idx] = v ? hb[(size_t)(c0 + c) * 3844 + gr * 62 + gc] : 0.f;
    }
    __syncthreads();
    for (int c = 0; c < 24; ++c) {
      const float* sc = s + c * 324 + ty * 18 + tx;
      float tap[9];
      #pragma unroll
      for (int di = 0; di < 3; ++di)
        #pragma unroll
        for (int dj = 0; dj < 3; ++dj) tap[di * 3 + dj] = sc[di * 18 + dj];
      #pragma unroll
      for (int k9 = 0; k9 < 9; ++k9) {
        const float* w = Wt + (size_t)(k9 * 48 + c0 + c) * 48;
        float tv = tap[k9];
        #pragma unroll
        for (int o = 0; o < 48; ++o) acc[o] = fmaf(tv, w[o], acc[o]);
      }
    }
  }
  // epilogue: +bt, 1x1 relu 48->128, 1x1 128->8, masked residual
  #pragma unroll
  for (int o = 0; o < 48; ++o) acc[o] += bt[o];
  float dx[8];
  #pragma unroll
  for (int k = 0; k < 8; ++k) dx[k] = b3[k];
  for (int o = 0; o < 128; ++o) {
    float v = b2[o];
    const float* w2 = W2 + o;                 // W2[c*128 + o]
    #pragma unroll
    for (int c = 0; c < 48; ++c) v = fmaf(acc[c], w2[c * 128], v);
    v = fmaxf(v, 0.f);
    const float* w3 = W3 + o * 8;
    #pragma unroll
    for (int k = 0; k < 8; ++k) dx[k] = fmaf(v, w3[k], dx[k]);
  }
  int pix = b * 4096 + (i0 + ty) * 64 + (j0 + tx);
  float mask = (noise[pix] <= 0.5f) ? 1.f : 0.f;
  const float* xp = x + (size_t)pix * 8;
  float* xo = x2 + (size_t)pix * 8;
  float a3 = 0.f;
  #pragma unroll
  for (int k = 0; k < 8; ++k) {
    float v = fmaf(dx[k], mask, xp[k]);
    xo[k] = v;
    if (k == 3) a3 = v;
  }
  alpha2[pix] = a3;
}

// ---------------------------------------------------------------------------
// K6: post_life maxpool + alive gating -> d_out
// ---------------------------------------------------------------------------
__global__ __launch_bounds__(256) void k_life(
    const float* __restrict__ x2, const float* __restrict__ alpha2,
    const float* __restrict__ prelife, float* __restrict__ out) {
  int pix = blockIdx.x * 256 + threadIdx.x;
  int hw = pix & 4095;
  int h = hw >> 6, w = hw & 63;
  const float* ab = alpha2 + (size_t)(pix - hw);
  float mx = -1e30f;
  #pragma unroll
  for (int di = -1; di <= 1; ++di) {
    if ((unsigned)(h + di) > 63u) continue;
    #pragma unroll
    for (int dj = -1; dj <= 1; ++dj) {
      if ((unsigned)(w + dj) > 63u) continue;
      mx = fmaxf(mx, ab[(h + di) * 64 + (w + dj)]);
    }
  }
  float life = (mx > 0.1f && prelife[pix] > 0.5f) ? 1.f : 0.f;
  const float* xp = x2 + (size_t)pix * 8;
  float* op = out + (size_t)pix * 8;
  #pragma unroll
  for (int k = 0; k < 8; ++k) op[k] = xp[k] * life;
}

// ---------------------------------------------------------------------------
extern "C" void kernel_launch(void* const* d_in, const int* in_sizes, int n_in,
                              void* d_out, int out_size, void* d_ws, size_t ws_size,
                              hipStream_t stream) {
  const float* x     = (const float*)d_in[0];
  const float* noise = (const float*)d_in[1];
  const float* Watt  = (const float*)d_in[2];
  const float* b_att = (const float*)d_in[3];
  const float* W1    = (const float*)d_in[4];
  const float* b1    = (const float*)d_in[5];
  const float* Wt    = (const float*)d_in[6];
  const float* bt    = (const float*)d_in[7];
  const float* W2    = (const float*)d_in[8];
  const float* b2    = (const float*)d_in[9];
  const float* W3    = (const float*)d_in[10];
  const float* b3    = (const float*)d_in[11];
  float* out = (float*)d_out;

  float* ws = (float*)d_ws;
  size_t o_y   = 0;                       // y_chw   [64*24*4096]  = 6291456
  size_t o_y2  = o_y + 6291456;           // y2_chw  [64*72*4096] = 18874368
  size_t o_h1  = o_y2 + 18874368;         // h1_chw  [64*48*62*62] = 11808768
  size_t o_y0  = o_h1 + 11808768;         // y0_hwc  [98304]
  size_t o_pre = o_y0 + 98304;            // prelife [262144]
  size_t o_att = o_pre + 262144;          // att_acc [648] + ssq [1]
  float* y_chw   = ws + o_y;
  float* y2_chw  = ws + o_y2;
  float* h1_chw  = ws + o_h1;
  float* y0_hwc  = ws + o_y0;
  float* prelife = ws + o_pre;
  float* att_acc = ws + o_att;
  float* ssq     = ws + o_att + 648;
  float* x2      = ws + o_y;              // alias: y dead after k_dw2
  float* alpha2  = ws + o_y + 2097152;

  k_perceive<<<1024, 256, 0, stream>>>(x, y_chw, y0_hwc, prelife, att_acc);
  k_att<<<768, 256, 0, stream>>>(y0_hwc, Watt, att_acc);
  k_dw2<<<1024, 256, 0, stream>>>(y_chw, att_acc, b_att, y2_chw, ssq);
  k_conv1<<<1024, 256, 0, stream>>>(y2_chw, W1, b1, ssq, h1_chw);
  k_convT_head<<<1024, 256, 0, stream>>>(h1_chw, Wt, bt, W2, b2, W3, b3,
                                         x, noise, x2, alpha2);
  k_life<<<1024, 256, 0, stream>>>(x2, alpha2, prelife, out);
}